// Round 3
// baseline (11957.044 us; speedup 1.0000x reference)
//
#include <hip/hip_runtime.h>

#define Tn 512
#define Bn 64
#define In 300
#define Hn 1000
#define G4H 4000
#define KP 1024   // padded K for recurrence (H=1000 -> 1024)
#define KI 320    // padded K for input GEMM (I=300 -> 320)
#define NB 250    // scan blocks: 250 * 4 hidden cols = 1000
#define NGROUP 16 // barrier groups (ceil(250/16))

typedef __attribute__((ext_vector_type(8))) short bf16x8;
typedef __attribute__((ext_vector_type(4))) float f32x4;
typedef unsigned int u32;
typedef unsigned short u16;

__device__ __forceinline__ u16 f2bf(float x) {
  union { float f; u32 u; } v; v.f = x;
  u32 r = (v.u + 0x7fffu + ((v.u >> 16) & 1u)) >> 16;
  return (u16)r;
}
__device__ __forceinline__ float bf2f(u16 s) {
  union { u32 u; float f; } v; v.u = ((u32)s) << 16;
  return v.f;
}
__device__ __forceinline__ float sigm(float x) { return 1.f / (1.f + __expf(-x)); }
__device__ __forceinline__ float tanh_f(float x) {
  float e = __expf(2.f * x);
  return 1.f - 2.f / (e + 1.f);
}

// ---------------------------------------------------------------- converts
__global__ void conv_pad(const float* __restrict__ src, u16* __restrict__ dst,
                         int rows, int scols, int dcols) {
  int idx = blockIdx.x * 256 + threadIdx.x;
  int total = rows * dcols;
  if (idx >= total) return;
  int r = idx / dcols, k = idx - r * dcols;
  float v = (k < scols) ? src[(size_t)r * scols + k] : 0.f;
  dst[idx] = f2bf(v);
}

// init h double-buffer (bf16, K-padded with zeros) + zero the barrier area
__global__ void init_scan(const float* __restrict__ h0, u16* __restrict__ hbuf,
                          u32* __restrict__ bar) {
  int idx = blockIdx.x * 256 + threadIdx.x;
  if (idx < 4096) bar[idx] = 0;
  if (idx >= 2 * Bn * KP) return;
  int which = idx >> 16;          // 64*1024 = 65536 per buffer
  int rem = idx & 65535;
  int b = rem >> 10, k = rem & (KP - 1);
  float v = (which == 0 && k < Hn) ? h0[b * Hn + k] : 0.f;
  hbuf[idx] = f2bf(v);
}

// ---------------------------------------------------------------- xg GEMM
// Writes xg in scan-friendly layout: xg[t][nb][b][16], slot s = g*4 + jl
// where hidden col j = 4*nb + jl, gate col n = g*1000 + j.
template<bool XF32>
__global__ void __launch_bounds__(256)
gemm_xg(const u16* __restrict__ A, const u16* __restrict__ Wb,
        const float* __restrict__ b_ih, const float* __restrict__ b_hh,
        void* __restrict__ xg_out) {
  const int lane = threadIdx.x & 63, w = threadIdx.x >> 6;
  const int m0 = blockIdx.x * 64, n0 = blockIdx.y * 64;
  f32x4 acc[4] = {};
  const int arow = m0 + w * 16 + (lane & 15);
  const int koff = (lane >> 4) * 8;
  int nrow[4];
#pragma unroll
  for (int nt = 0; nt < 4; ++nt) {
    int n = n0 + nt * 16 + (lane & 15);
    nrow[nt] = (n < G4H) ? n : (G4H - 1);
  }
  for (int kc = 0; kc < KI / 32; ++kc) {
    bf16x8 a = *(const bf16x8*)(A + (size_t)arow * KI + kc * 32 + koff);
#pragma unroll
    for (int nt = 0; nt < 4; ++nt) {
      bf16x8 bb = *(const bf16x8*)(Wb + (size_t)nrow[nt] * KI + kc * 32 + koff);
      acc[nt] = __builtin_amdgcn_mfma_f32_16x16x32_bf16(a, bb, acc[nt], 0, 0, 0);
    }
  }
#pragma unroll
  for (int nt = 0; nt < 4; ++nt) {
    int col = n0 + nt * 16 + (lane & 15);
    if (col >= G4H) continue;
    float bias = b_ih[col] + b_hh[col];
    u32 g = (u32)col / 1000u;
    int j = col - (int)g * 1000;
    int nbk = j >> 2, jl = j & 3;
    int s = ((int)g << 2) | jl;
    int mrow = m0 + w * 16 + (lane >> 4) * 4;
#pragma unroll
    for (int r = 0; r < 4; ++r) {
      int m = mrow + r;
      int t = m >> 6, b = m & 63;
      float v = acc[nt][r] + bias;
      size_t o = (((size_t)t * NB + nbk) * 64 + b) * 16 + s;
      if constexpr (XF32) ((float*)xg_out)[o] = v;
      else                ((u16*)xg_out)[o] = f2bf(v);
    }
  }
}

// ---------------------------------------------------------------- barrier
// Monotonic two-level barrier, 256-B-spaced lines, broadcast tree.
// bar[0]                 : root counter (monotonic, +1 per group per step)
// bar[64 + g*64]         : group-g arrival counter (monotonic)
// bar[2048 + g*64]       : group-g generation line (written by root winner)
__device__ __forceinline__ void bar_arrive(u32* bar, u32 step) {
  const int g = (int)blockIdx.x >> 4;
  const int gsz0 = NB - (g << 4);
  const u32 gsz = (u32)(gsz0 < 16 ? gsz0 : 16);
  u32 old = __hip_atomic_fetch_add(bar + 64 + g * 64, 1u, __ATOMIC_ACQ_REL,
                                   __HIP_MEMORY_SCOPE_AGENT);
  if (old == gsz * step - 1u) {
    u32 r = __hip_atomic_fetch_add(bar, 1u, __ATOMIC_ACQ_REL,
                                   __HIP_MEMORY_SCOPE_AGENT);
    if (r == (u32)NGROUP * step - 1u) {
#pragma unroll
      for (int gg = 0; gg < NGROUP; ++gg)
        __hip_atomic_store(bar + 2048 + gg * 64, step, __ATOMIC_RELEASE,
                           __HIP_MEMORY_SCOPE_AGENT);
    }
  }
}
__device__ __forceinline__ void bar_wait(u32* bar, u32 step) {
  const int g = (int)blockIdx.x >> 4;
  u32* gen = bar + 2048 + g * 64;
  while (__hip_atomic_load(gen, __ATOMIC_RELAXED, __HIP_MEMORY_SCOPE_AGENT) < step) {
    __builtin_amdgcn_s_sleep(1);
  }
  (void)__hip_atomic_load(gen, __ATOMIC_ACQUIRE, __HIP_MEMORY_SCOPE_AGENT);
}

// ---------------------------------------------------------------- scan
// 250 blocks x 256 threads. Block nb owns hidden cols [4nb, 4nb+4) ->
// 16 gate rows s = g*4+jl. W_hh slice lives in REGISTERS (128 VGPR/lane of
// B-fragments). Wave w computes gates for batch rows 16w..16w+15 via two
// independent 16-deep MFMA chains; acc0 is initialized from xg (coalesced
// [t][nb][b][16] layout, b = w*16 + q*4 + r  <-- the w*16 was the R2 bug).
// Pointwise c-state in registers per thread (b = tid>>2, jl = tid&3).
template<bool XF32>
__global__ void __launch_bounds__(256, 1)
lstm_scan(const float* __restrict__ Whh, const float* __restrict__ c0,
          const void* __restrict__ xg_, u16* __restrict__ hbuf,
          float* __restrict__ out, u32* __restrict__ bar) {
  __shared__ float Sc[4][16][17];
  const int tid = threadIdx.x;
  const int lane = tid & 63;
  const int w = tid >> 6;
  const int nb = blockIdx.x;
  const int s = lane & 15;        // gate-row index within block (B col)
  const int q = lane >> 4;        // k-quarter

  // ---- stage this lane's W_hh B-fragments into registers (once) ----
  bf16x8 wreg[32];
  {
    const int grow = (s >> 2) * Hn + nb * 4 + (s & 3);
    const float* wrow = Whh + (size_t)grow * Hn;
#pragma unroll
    for (int kc = 0; kc < 32; ++kc) {
      const int k0 = kc * 32 + q * 8;
      bf16x8 v;
#pragma unroll
      for (int j = 0; j < 8; ++j) {
        float f = (k0 + j < Hn) ? wrow[k0 + j] : 0.f;
        v[j] = (short)f2bf(f);
      }
      wreg[kc] = v;
    }
  }

  const int b = tid >> 2;
  const int jl = tid & 3;
  const int jh = nb * 4 + jl;
  float c = c0[b * Hn + jh];

  const float* xf = (const float*)xg_;
  const u16* xh = (const u16*)xg_;

  // prefetch xg for t=0 (C-layout acc init: batch rows w*16 + q*4 + r, col s)
  float xa0, xa1, xa2, xa3;
  {
    size_t base = (((size_t)0 * NB + nb) * 64 + w * 16 + q * 4) * 16 + s;
    if constexpr (XF32) {
      xa0 = xf[base]; xa1 = xf[base + 16];
      xa2 = xf[base + 32]; xa3 = xf[base + 48];
    } else {
      xa0 = bf2f(xh[base]); xa1 = bf2f(xh[base + 16]);
      xa2 = bf2f(xh[base + 32]); xa3 = bf2f(xh[base + 48]);
    }
  }

  for (int t = 0; t < Tn; ++t) {
    const u16* hc = hbuf + (size_t)(t & 1) * Bn * KP;
    u16* hn = hbuf + (size_t)((t + 1) & 1) * Bn * KP;
    const u16* hptr = hc + (size_t)(w * 16 + s) * KP + q * 8;

    f32x4 a0 = {xa0, xa1, xa2, xa3};
    f32x4 a1 = {0.f, 0.f, 0.f, 0.f};
#pragma unroll
    for (int kc = 0; kc < 16; ++kc) {
      bf16x8 av = *(const bf16x8*)(hptr + kc * 32);
      a0 = __builtin_amdgcn_mfma_f32_16x16x32_bf16(av, wreg[kc], a0, 0, 0, 0);
    }
#pragma unroll
    for (int kc = 16; kc < 32; ++kc) {
      bf16x8 av = *(const bf16x8*)(hptr + kc * 32);
      a1 = __builtin_amdgcn_mfma_f32_16x16x32_bf16(av, wreg[kc], a1, 0, 0, 0);
    }

    // redistribute C within the wave via LDS (writer wave == reader wave)
#pragma unroll
    for (int r = 0; r < 4; ++r)
      Sc[w][q * 4 + r][s] = a0[r] + a1[r];

    float gi = Sc[w][b & 15][jl];
    float gf = Sc[w][b & 15][4 + jl];
    float gg = Sc[w][b & 15][8 + jl];
    float go = Sc[w][b & 15][12 + jl];
    float iv = sigm(gi), fv = sigm(gf), gv = tanh_f(gg), ov = sigm(go);
    c = fv * c + iv * gv;
    float h = ov * tanh_f(c);
    hn[b * KP + jh] = f2bf(h);

    if (t != Tn - 1) {
      __syncthreads();                       // all hn stores issued
      if (tid == 0) bar_arrive(bar, (u32)(t + 1));

      // overlap with the barrier: out store + next-step xg prefetch
      out[((size_t)t * Bn + b) * Hn + jh] = h;
      {
        size_t base =
            (((size_t)(t + 1) * NB + nb) * 64 + w * 16 + q * 4) * 16 + s;
        if constexpr (XF32) {
          xa0 = xf[base]; xa1 = xf[base + 16];
          xa2 = xf[base + 32]; xa3 = xf[base + 48];
        } else {
          xa0 = bf2f(xh[base]); xa1 = bf2f(xh[base + 16]);
          xa2 = bf2f(xh[base + 32]); xa3 = bf2f(xh[base + 48]);
        }
      }
      if (tid == 0) bar_wait(bar, (u32)(t + 1));
      __syncthreads();                       // release all waves into step t+1
    } else {
      out[((size_t)t * Bn + b) * Hn + jh] = h;
    }
  }
}

// ---------------------------------------------------------------- launch
extern "C" void kernel_launch(void* const* d_in, const int* in_sizes, int n_in,
                              void* d_out, int out_size, void* d_ws, size_t ws_size,
                              hipStream_t stream) {
  const float* inputs = (const float*)d_in[0];
  const float* h0 = (const float*)d_in[1];
  const float* c0 = (const float*)d_in[2];
  const float* W_ih = (const float*)d_in[3];
  const float* W_hh = (const float*)d_in[4];
  const float* b_ih = (const float*)d_in[5];
  const float* b_hh = (const float*)d_in[6];
  float* out = (float*)d_out;

  char* ws = (char*)d_ws;
  size_t off = 0;
  auto carve = [&](size_t bytes) {
    char* p = ws + off;
    off = (off + bytes + 255) & ~(size_t)255;
    return p;
  };
  u32* bar = (u32*)carve(16384);
  u16* in_bf = (u16*)carve((size_t)Tn * Bn * KI * 2);
  u16* wih_bf = (u16*)carve((size_t)G4H * KI * 2);
  u16* hbuf = (u16*)carve((size_t)2 * Bn * KP * 2);
  size_t fixed = off;
  size_t xg_f32 = (size_t)Tn * NB * 64 * 16 * 4;
  bool xf32 = (ws_size >= fixed + xg_f32);
  void* xg = (void*)carve(xf32 ? xg_f32 : xg_f32 / 2);

  int tot_in = Tn * Bn * KI;
  conv_pad<<<dim3((tot_in + 255) / 256), dim3(256), 0, stream>>>(
      inputs, in_bf, Tn * Bn, In, KI);
  int tot_w = G4H * KI;
  conv_pad<<<dim3((tot_w + 255) / 256), dim3(256), 0, stream>>>(
      W_ih, wih_bf, G4H, In, KI);
  init_scan<<<dim3(512), dim3(256), 0, stream>>>(h0, hbuf, bar);

  if (xf32) {
    gemm_xg<true><<<dim3(Tn * Bn / 64, (G4H + 63) / 64), dim3(256), 0, stream>>>(
        in_bf, wih_bf, b_ih, b_hh, xg);
    lstm_scan<true><<<dim3(NB), dim3(256), 0, stream>>>(
        W_hh, c0, xg, hbuf, out, bar);
  } else {
    gemm_xg<false><<<dim3(Tn * Bn / 64, (G4H + 63) / 64), dim3(256), 0, stream>>>(
        in_bf, wih_bf, b_ih, b_hh, xg);
    lstm_scan<false><<<dim3(NB), dim3(256), 0, stream>>>(
        W_hh, c0, xg, hbuf, out, bar);
  }
}

// Round 4
// 6208.258 us; speedup vs baseline: 1.9260x; 1.9260x over previous
//
#include <hip/hip_runtime.h>

#define Tn 512
#define Bn 64
#define In 300
#define Hn 1000
#define G4H 4000
#define KP 1024   // padded K for recurrence (H=1000 -> 1024)
#define KI 320    // padded K for input GEMM (I=300 -> 320)
#define NB 250    // scan blocks: 250 * 4 hidden cols = 1000
#define NGROUP 16 // barrier groups (ceil(250/16))

typedef __attribute__((ext_vector_type(8))) short bf16x8;
typedef __attribute__((ext_vector_type(4))) float f32x4;
typedef unsigned int u32;
typedef unsigned short u16;
typedef unsigned long long u64;

__device__ __forceinline__ u16 f2bf(float x) {
  union { float f; u32 u; } v; v.f = x;
  u32 r = (v.u + 0x7fffu + ((v.u >> 16) & 1u)) >> 16;
  return (u16)r;
}
__device__ __forceinline__ float bf2f(u16 s) {
  union { u32 u; float f; } v; v.u = ((u32)s) << 16;
  return v.f;
}
__device__ __forceinline__ float sigm(float x) { return 1.f / (1.f + __expf(-x)); }
__device__ __forceinline__ float tanh_f(float x) {
  float e = __expf(2.f * x);
  return 1.f - 2.f / (e + 1.f);
}

// Relaxed agent-scope accesses: routed to the coherent point (L3) per-access,
// with NO buffer_wbl2 / buffer_inv cache maintenance (that was the ~20us/step).
__device__ __forceinline__ u64 aload64(const u64* p) {
  return __hip_atomic_load((u64*)p, __ATOMIC_RELAXED, __HIP_MEMORY_SCOPE_AGENT);
}
__device__ __forceinline__ void astore64(u64* p, u64 v) {
  __hip_atomic_store(p, v, __ATOMIC_RELAXED, __HIP_MEMORY_SCOPE_AGENT);
}

// ---------------------------------------------------------------- converts
__global__ void conv_pad(const float* __restrict__ src, u16* __restrict__ dst,
                         int rows, int scols, int dcols) {
  int idx = blockIdx.x * 256 + threadIdx.x;
  int total = rows * dcols;
  if (idx >= total) return;
  int r = idx / dcols, k = idx - r * dcols;
  float v = (k < scols) ? src[(size_t)r * scols + k] : 0.f;
  dst[idx] = f2bf(v);
}

// init h double-buffer (bf16, K-padded with zeros) + zero the barrier area
__global__ void init_scan(const float* __restrict__ h0, u16* __restrict__ hbuf,
                          u32* __restrict__ bar) {
  int idx = blockIdx.x * 256 + threadIdx.x;
  if (idx < 4096) bar[idx] = 0;
  if (idx >= 2 * Bn * KP) return;
  int which = idx >> 16;          // 64*1024 = 65536 per buffer
  int rem = idx & 65535;
  int b = rem >> 10, k = rem & (KP - 1);
  float v = (which == 0 && k < Hn) ? h0[b * Hn + k] : 0.f;
  hbuf[idx] = f2bf(v);
}

// ---------------------------------------------------------------- xg GEMM
// Writes xg in scan-friendly layout: xg[t][nb][b][16], slot s = g*4 + jl
// where hidden col j = 4*nb + jl, gate col n = g*1000 + j.
template<bool XF32>
__global__ void __launch_bounds__(256)
gemm_xg(const u16* __restrict__ A, const u16* __restrict__ Wb,
        const float* __restrict__ b_ih, const float* __restrict__ b_hh,
        void* __restrict__ xg_out) {
  const int lane = threadIdx.x & 63, w = threadIdx.x >> 6;
  const int m0 = blockIdx.x * 64, n0 = blockIdx.y * 64;
  f32x4 acc[4] = {};
  const int arow = m0 + w * 16 + (lane & 15);
  const int koff = (lane >> 4) * 8;
  int nrow[4];
#pragma unroll
  for (int nt = 0; nt < 4; ++nt) {
    int n = n0 + nt * 16 + (lane & 15);
    nrow[nt] = (n < G4H) ? n : (G4H - 1);
  }
  for (int kc = 0; kc < KI / 32; ++kc) {
    bf16x8 a = *(const bf16x8*)(A + (size_t)arow * KI + kc * 32 + koff);
#pragma unroll
    for (int nt = 0; nt < 4; ++nt) {
      bf16x8 bb = *(const bf16x8*)(Wb + (size_t)nrow[nt] * KI + kc * 32 + koff);
      acc[nt] = __builtin_amdgcn_mfma_f32_16x16x32_bf16(a, bb, acc[nt], 0, 0, 0);
    }
  }
#pragma unroll
  for (int nt = 0; nt < 4; ++nt) {
    int col = n0 + nt * 16 + (lane & 15);
    if (col >= G4H) continue;
    float bias = b_ih[col] + b_hh[col];
    u32 g = (u32)col / 1000u;
    int j = col - (int)g * 1000;
    int nbk = j >> 2, jl = j & 3;
    int s = ((int)g << 2) | jl;
    int mrow = m0 + w * 16 + (lane >> 4) * 4;
#pragma unroll
    for (int r = 0; r < 4; ++r) {
      int m = mrow + r;
      int t = m >> 6, b = m & 63;
      float v = acc[nt][r] + bias;
      size_t o = (((size_t)t * NB + nbk) * 64 + b) * 16 + s;
      if constexpr (XF32) ((float*)xg_out)[o] = v;
      else                ((u16*)xg_out)[o] = f2bf(v);
    }
  }
}

// ---------------------------------------------------------------- barrier
// Monotonic two-level barrier, 256-B-spaced lines, broadcast tree.
// ALL RELAXED: no release/acquire -> no L2 writeback/invalidate per step.
// Ordering is provided by __syncthreads (s_waitcnt vmcnt(0) before s_barrier)
// around the data stores/loads, which themselves bypass to the coherent point.
// bar[0]                 : root counter (monotonic, +1 per group per step)
// bar[64 + g*64]         : group-g arrival counter (monotonic)
// bar[2048 + g*64]       : group-g generation line (written by root winner)
__device__ __forceinline__ void bar_arrive(u32* bar, u32 step) {
  const int g = (int)blockIdx.x >> 4;
  const int gsz0 = NB - (g << 4);
  const u32 gsz = (u32)(gsz0 < 16 ? gsz0 : 16);
  u32 old = __hip_atomic_fetch_add(bar + 64 + g * 64, 1u, __ATOMIC_RELAXED,
                                   __HIP_MEMORY_SCOPE_AGENT);
  if (old == gsz * step - 1u) {
    u32 r = __hip_atomic_fetch_add(bar, 1u, __ATOMIC_RELAXED,
                                   __HIP_MEMORY_SCOPE_AGENT);
    if (r == (u32)NGROUP * step - 1u) {
#pragma unroll
      for (int gg = 0; gg < NGROUP; ++gg)
        __hip_atomic_store(bar + 2048 + gg * 64, step, __ATOMIC_RELAXED,
                           __HIP_MEMORY_SCOPE_AGENT);
    }
  }
}
__device__ __forceinline__ void bar_wait(u32* bar, u32 step) {
  const int g = (int)blockIdx.x >> 4;
  u32* gen = bar + 2048 + g * 64;
  while (__hip_atomic_load(gen, __ATOMIC_RELAXED, __HIP_MEMORY_SCOPE_AGENT) < step) {
    __builtin_amdgcn_s_sleep(1);
  }
}

// ---------------------------------------------------------------- scan
// 250 blocks x 256 threads. Block nb owns hidden cols [4nb, 4nb+4).
// W_hh slice in registers (128 VGPR of B-frags). h double-buffer moves via
// relaxed agent-scope u64 atomics (write-through / read-through at L3).
template<bool XF32>
__global__ void __launch_bounds__(256, 1)
lstm_scan(const float* __restrict__ Whh, const float* __restrict__ c0,
          const void* __restrict__ xg_, u64* __restrict__ hbu,
          float* __restrict__ out, u32* __restrict__ bar) {
  __shared__ float Sc[4][16][17];
  __shared__ __align__(8) u16 hs[64][4];
  const int tid = threadIdx.x;
  const int lane = tid & 63;
  const int w = tid >> 6;
  const int nb = blockIdx.x;
  const int s = lane & 15;        // gate-row index within block (B col)
  const int q = lane >> 4;        // k-quarter

  // ---- stage this lane's W_hh B-fragments into registers (once) ----
  bf16x8 wreg[32];
  {
    const int grow = (s >> 2) * Hn + nb * 4 + (s & 3);
    const float* wrow = Whh + (size_t)grow * Hn;
#pragma unroll
    for (int kc = 0; kc < 32; ++kc) {
      const int k0 = kc * 32 + q * 8;
      bf16x8 v;
#pragma unroll
      for (int j = 0; j < 8; ++j) {
        float f = (k0 + j < Hn) ? wrow[k0 + j] : 0.f;
        v[j] = (short)f2bf(f);
      }
      wreg[kc] = v;
    }
  }

  const int b = tid >> 2;
  const int jl = tid & 3;
  const int jh = nb * 4 + jl;
  float c = c0[b * Hn + jh];

  const float* xf = (const float*)xg_;
  const u16* xh = (const u16*)xg_;

  // prefetch xg for t=0 (C-layout acc init: batch rows w*16 + q*4 + r, col s)
  float xa0, xa1, xa2, xa3;
  {
    size_t base = (((size_t)0 * NB + nb) * 64 + w * 16 + q * 4) * 16 + s;
    if constexpr (XF32) {
      xa0 = xf[base]; xa1 = xf[base + 16];
      xa2 = xf[base + 32]; xa3 = xf[base + 48];
    } else {
      xa0 = bf2f(xh[base]); xa1 = bf2f(xh[base + 16]);
      xa2 = bf2f(xh[base + 32]); xa3 = bf2f(xh[base + 48]);
    }
  }

  // u64 geometry: one h buffer = Bn*KP/4 = 16384 u64; row stride 256 u64.
  for (int t = 0; t < Tn; ++t) {
    const u64* hc = hbu + (size_t)(t & 1) * 16384;
    u64* hn = hbu + (size_t)((t + 1) & 1) * 16384;
    const u64* hrow = hc + (size_t)(w * 16 + s) * 256 + q * 2;

    f32x4 a0 = {xa0, xa1, xa2, xa3};
    f32x4 a1 = {0.f, 0.f, 0.f, 0.f};
#pragma unroll
    for (int kc = 0; kc < 16; ++kc) {
      union { u64 d[2]; bf16x8 v; } av;
      av.d[0] = aload64(hrow + kc * 8);
      av.d[1] = aload64(hrow + kc * 8 + 1);
      a0 = __builtin_amdgcn_mfma_f32_16x16x32_bf16(av.v, wreg[kc], a0, 0, 0, 0);
    }
#pragma unroll
    for (int kc = 16; kc < 32; ++kc) {
      union { u64 d[2]; bf16x8 v; } av;
      av.d[0] = aload64(hrow + kc * 8);
      av.d[1] = aload64(hrow + kc * 8 + 1);
      a1 = __builtin_amdgcn_mfma_f32_16x16x32_bf16(av.v, wreg[kc], a1, 0, 0, 0);
    }

    // redistribute C within the wave via LDS (writer wave == reader wave)
#pragma unroll
    for (int r = 0; r < 4; ++r)
      Sc[w][q * 4 + r][s] = a0[r] + a1[r];

    float gi = Sc[w][b & 15][jl];
    float gf = Sc[w][b & 15][4 + jl];
    float gg = Sc[w][b & 15][8 + jl];
    float go = Sc[w][b & 15][12 + jl];
    float iv = sigm(gi), fv = sigm(gf), gv = tanh_f(gg), ov = sigm(go);
    c = fv * c + iv * gv;
    float h = ov * tanh_f(c);

    out[((size_t)t * Bn + b) * Hn + jh] = h;     // normal cached store
    hs[b][jl] = f2bf(h);                          // stage for packed u64 store

    if (t != Tn - 1) {
      __syncthreads();                           // hs visible block-wide
      if (tid < 64) {
        u64 hv = *(const u64*)hs[tid];           // 4 bf16 packed
        astore64(hn + (size_t)tid * 256 + nb, hv);
      }
      __syncthreads();                           // vmcnt(0): h at L3
      if (tid == 0) bar_arrive(bar, (u32)(t + 1));

      // overlap the barrier wait: next-step xg prefetch (normal loads)
      {
        size_t base =
            (((size_t)(t + 1) * NB + nb) * 64 + w * 16 + q * 4) * 16 + s;
        if constexpr (XF32) {
          xa0 = xf[base]; xa1 = xf[base + 16];
          xa2 = xf[base + 32]; xa3 = xf[base + 48];
        } else {
          xa0 = bf2f(xh[base]); xa1 = bf2f(xh[base + 16]);
          xa2 = bf2f(xh[base + 32]); xa3 = bf2f(xh[base + 48]);
        }
      }
      if (tid == 0) bar_wait(bar, (u32)(t + 1));
      __syncthreads();                           // release all waves into t+1
    }
  }
}

// ---------------------------------------------------------------- launch
extern "C" void kernel_launch(void* const* d_in, const int* in_sizes, int n_in,
                              void* d_out, int out_size, void* d_ws, size_t ws_size,
                              hipStream_t stream) {
  const float* inputs = (const float*)d_in[0];
  const float* h0 = (const float*)d_in[1];
  const float* c0 = (const float*)d_in[2];
  const float* W_ih = (const float*)d_in[3];
  const float* W_hh = (const float*)d_in[4];
  const float* b_ih = (const float*)d_in[5];
  const float* b_hh = (const float*)d_in[6];
  float* out = (float*)d_out;

  char* ws = (char*)d_ws;
  size_t off = 0;
  auto carve = [&](size_t bytes) {
    char* p = ws + off;
    off = (off + bytes + 255) & ~(size_t)255;
    return p;
  };
  u32* bar = (u32*)carve(16384);
  u16* in_bf = (u16*)carve((size_t)Tn * Bn * KI * 2);
  u16* wih_bf = (u16*)carve((size_t)G4H * KI * 2);
  u16* hbuf = (u16*)carve((size_t)2 * Bn * KP * 2);
  size_t fixed = off;
  size_t xg_f32 = (size_t)Tn * NB * 64 * 16 * 4;
  bool xf32 = (ws_size >= fixed + xg_f32);
  void* xg = (void*)carve(xf32 ? xg_f32 : xg_f32 / 2);

  int tot_in = Tn * Bn * KI;
  conv_pad<<<dim3((tot_in + 255) / 256), dim3(256), 0, stream>>>(
      inputs, in_bf, Tn * Bn, In, KI);
  int tot_w = G4H * KI;
  conv_pad<<<dim3((tot_w + 255) / 256), dim3(256), 0, stream>>>(
      W_ih, wih_bf, G4H, In, KI);
  init_scan<<<dim3(512), dim3(256), 0, stream>>>(h0, hbuf, bar);

  if (xf32) {
    gemm_xg<true><<<dim3(Tn * Bn / 64, (G4H + 63) / 64), dim3(256), 0, stream>>>(
        in_bf, wih_bf, b_ih, b_hh, xg);
    lstm_scan<true><<<dim3(NB), dim3(256), 0, stream>>>(
        W_hh, c0, xg, (u64*)hbuf, out, bar);
  } else {
    gemm_xg<false><<<dim3(Tn * Bn / 64, (G4H + 63) / 64), dim3(256), 0, stream>>>(
        in_bf, wih_bf, b_ih, b_hh, xg);
    lstm_scan<false><<<dim3(NB), dim3(256), 0, stream>>>(
        W_hh, c0, xg, (u64*)hbuf, out, bar);
  }
}